// Round 13
// baseline (752.028 us; speedup 1.0000x reference)
//
#include <hip/hip_runtime.h>

// Problem constants (B=4, N=2048, C=256, H=8, D=32, keep = int(2048*0.3) = 614)
#define BDIM 4
#define NSEQ 2048
#define CDIM 256
#define NHEADS 8
#define QB 4                     // query rows per block (1 per wave)
#define NT2 32                   // per-wave tiles: 32 tiles x 16 cols = 512 cols
#define NKEEP 614                // int(2048 * (1.0 - 0.7))
#define SSTR 2056                // sbuf row stride (bank stagger)
#define ATTN_SCALE 0.17677669529663688f  // 32^-0.5

typedef __bf16 bf16x8 __attribute__((ext_vector_type(8)));
typedef float  f32x4  __attribute__((ext_vector_type(4)));

// -------------------------------------------------------------------------
// GEMM: C[M][Nt] = A[M][K] @ W[Nt][K]^T + bias[Nt]   (unchanged, validated)
// -------------------------------------------------------------------------
__global__ __launch_bounds__(256) void gemm_nt_bias(
    const float* __restrict__ A, const float* __restrict__ W,
    const float* __restrict__ bias, float* __restrict__ C,
    int M, int Nt, int K)
{
    __shared__ __align__(16) float As[32][68];
    __shared__ __align__(16) float Ws[32][68];
    const int tid = threadIdx.x;
    const int bm = blockIdx.x * 64;
    const int bn = blockIdx.y * 64;
    const int tm = tid >> 4;
    const int tn = tid & 15;
    const int lr = tid >> 2;
    const int lq = tid & 3;
    const float* Ap = A + (size_t)(bm + lr) * K + lq * 8;
    const float* Wp = W + (size_t)(bn + lr) * K + lq * 8;
    float acc[4][4] = {};

    for (int k0 = 0; k0 < K; k0 += 32) {
        float4 a0 = *(const float4*)(Ap + k0);
        float4 a1 = *(const float4*)(Ap + k0 + 4);
        float4 w0 = *(const float4*)(Wp + k0);
        float4 w1 = *(const float4*)(Wp + k0 + 4);
        __syncthreads();
        const int kq = lq * 8;
        As[kq+0][lr]=a0.x; As[kq+1][lr]=a0.y; As[kq+2][lr]=a0.z; As[kq+3][lr]=a0.w;
        As[kq+4][lr]=a1.x; As[kq+5][lr]=a1.y; As[kq+6][lr]=a1.z; As[kq+7][lr]=a1.w;
        Ws[kq+0][lr]=w0.x; Ws[kq+1][lr]=w0.y; Ws[kq+2][lr]=w0.z; Ws[kq+3][lr]=w0.w;
        Ws[kq+4][lr]=w1.x; Ws[kq+5][lr]=w1.y; Ws[kq+6][lr]=w1.z; Ws[kq+7][lr]=w1.w;
        __syncthreads();
        #pragma unroll
        for (int k = 0; k < 32; ++k) {
            float4 av = *(const float4*)&As[k][tm*4];
            float4 wv = *(const float4*)&Ws[k][tn*4];
            acc[0][0] += av.x*wv.x; acc[0][1] += av.x*wv.y; acc[0][2] += av.x*wv.z; acc[0][3] += av.x*wv.w;
            acc[1][0] += av.y*wv.x; acc[1][1] += av.y*wv.y; acc[1][2] += av.y*wv.z; acc[1][3] += av.y*wv.w;
            acc[2][0] += av.z*wv.x; acc[2][1] += av.z*wv.y; acc[2][2] += av.z*wv.z; acc[2][3] += av.z*wv.w;
            acc[3][0] += av.w*wv.x; acc[3][1] += av.w*wv.y; acc[3][2] += av.w*wv.z; acc[3][3] += av.w*wv.w;
        }
    }
    float4 bb = *(const float4*)(bias + bn + tn*4);
    #pragma unroll
    for (int i = 0; i < 4; ++i) {
        float4 o;
        o.x = acc[i][0] + bb.x;
        o.y = acc[i][1] + bb.y;
        o.z = acc[i][2] + bb.z;
        o.w = acc[i][3] + bb.w;
        *(float4*)(C + (size_t)(bm + tm*4 + i) * Nt + bn + tn*4) = o;
    }
}

// -------------------------------------------------------------------------
// In-place K repack: fp32 -> u32 packed (bf16_hi << 16) | bf16_lo.
// K section of qkv [b][n][1][*] is consumed ONLY by sparse_attn phase B.
// -------------------------------------------------------------------------
__global__ __launch_bounds__(256) void pack_k(float* __restrict__ qkv)
{
    const size_t i = (size_t)blockIdx.x * 256 + threadIdx.x;  // BDIM*NSEQ*64 float4 slots
    const size_t row = i >> 6;
    const int c4 = (int)(i & 63);
    float* p = qkv + row * 768 + 256 + c4 * 4;
    float4 v = *(const float4*)p;
    float xs[4] = { v.x, v.y, v.z, v.w };
    unsigned int o[4];
    #pragma unroll
    for (int j = 0; j < 4; ++j) {
        float x = xs[j];
        __bf16 hb = (__bf16)x;                       // RNE
        __bf16 lb = (__bf16)(x - (float)hb);
        o[j] = ((unsigned int)__builtin_bit_cast(unsigned short, hb) << 16)
             |  (unsigned int)__builtin_bit_cast(unsigned short, lb);
    }
    uint4 w4; w4.x = o[0]; w4.y = o[1]; w4.z = o[2]; w4.w = o[3];
    *(uint4*)p = w4;
}

// -------------------------------------------------------------------------
// Fused sparse attention. Phase B now uses MFMA (16x16x32 bf16, M=16 with
// 12 zero rows): S = Qh*Kh + Qh*Kl + Ql*Kh, fp32 accumulation (err ~6e-6).
// A-frag: lane -> row = l&15 (<4 real), k = 8*(l>>4)+j.
// B-frag: lane -> col = l&15,            k = 8*(l>>4)+j.
// D (m89): col = lane&15, row = (lane>>4)*4 + reg  -> lanes 0..15 hold all
// 4 real rows. Phases C/D/E identical to the validated round-12 kernel.
// -------------------------------------------------------------------------
__device__ __forceinline__ unsigned int f2key(float f) {
    unsigned int u = __float_as_uint(f);
    return (u & 0x80000000u) ? ~u : (u | 0x80000000u);  // monotone order-preserving
}

#define RBAR() do { asm volatile("s_waitcnt lgkmcnt(0)" ::: "memory"); \
                    __builtin_amdgcn_s_barrier();                      \
                    asm volatile("" ::: "memory"); } while (0)
#define LGKM0() asm volatile("s_waitcnt lgkmcnt(0)" ::: "memory")

// unpack 8 packed u32 -> hi/lo bf16x8 fragments (8 x v_perm_b32)
#define UNPK(U0, U1, BH, BL) do {                                             \
        uint4 hw_, lw_;                                                       \
        hw_.x = __builtin_amdgcn_perm((U0).y, (U0).x, 0x07060302u);           \
        lw_.x = __builtin_amdgcn_perm((U0).y, (U0).x, 0x05040100u);           \
        hw_.y = __builtin_amdgcn_perm((U0).w, (U0).z, 0x07060302u);           \
        lw_.y = __builtin_amdgcn_perm((U0).w, (U0).z, 0x05040100u);           \
        hw_.z = __builtin_amdgcn_perm((U1).y, (U1).x, 0x07060302u);           \
        lw_.z = __builtin_amdgcn_perm((U1).y, (U1).x, 0x05040100u);           \
        hw_.w = __builtin_amdgcn_perm((U1).w, (U1).z, 0x07060302u);           \
        lw_.w = __builtin_amdgcn_perm((U1).w, (U1).z, 0x05040100u);           \
        BH = __builtin_bit_cast(bf16x8, hw_);                                 \
        BL = __builtin_bit_cast(bf16x8, lw_);                                 \
    } while (0)

__global__ __launch_bounds__(256, 4) void sparse_attn(
    const float* __restrict__ qkv, float* __restrict__ aout)
{
    __shared__ __align__(16) float  sbuf[QB * SSTR];        // 32.1 KB scores / p-values
    __shared__ __align__(16) unsigned int hist[QB * 256];   // 4 KB
    __shared__ unsigned int prefS[QB];
    __shared__ int   remS[QB];
    __shared__ float zS[QB];

    const int tid = threadIdx.x;
    const int w   = tid >> 6;       // wave id = row id (0..3) = column-range owner
    const int l   = tid & 63;
    const int p   = l & 3;          // phase-E quad lane: dims [4p,4p+4) & [16+4p,..)
    const int jg  = l >> 2;         // phase-E: row within a 16-row tile

    const int blk = blockIdx.x;
    const int nqb = NSEQ / QB;      // 512
    const int bh  = blk / nqb;
    const int qblk = blk % nqb;
    const int b = bh / NHEADS, h = bh % NHEADS;
    const int n0 = qblk * QB;

    const float* base = qkv + (size_t)b * NSEQ * 768;
    // phase-B K pointer (packed u32): col = 512w + 16t + (l&15), k-base = (l>>4)*8
    const float* kbase0 = base + 256 + h * 32 + (l >> 4) * 8
                        + (size_t)((w << 9) + (l & 15)) * 768;
#define KADDR(t) ((const unsigned int*)(kbase0 + (size_t)(t) * (16 * 768)))
    // phase-E V pointer: col = 512w + 16t + jg, dims 4p + {0,16}
    const float* vptr = base + 512 + h * 32 + p * 4 + (size_t)((w << 9) + jg) * 768;
#define VADDR(t) (vptr + (size_t)(t) * (16 * 768))

    // ---- A-fragments: Q rows 0..3 (rows 4..15 zero), pre-scaled, split hi/lo ----
    bf16x8 ah, al;
    {
        #pragma unroll
        for (int j = 0; j < 8; ++j) { ah[j] = (__bf16)0.f; al[j] = (__bf16)0.f; }
        if ((l & 15) < QB) {
            const float* gq = base + (size_t)(n0 + (l & 15)) * 768 + h * 32 + (l >> 4) * 8;
            #pragma unroll
            for (int j = 0; j < 8; ++j) {
                float x = gq[j] * ATTN_SCALE;
                __bf16 hb = (__bf16)x;
                ah[j] = hb;
                al[j] = (__bf16)(x - (float)hb);
            }
        }
    }
    // zero pass-3 histogram (filled inline during phase B)
    {
        uint4 z4; z4.x = 0u; z4.y = 0u; z4.z = 0u; z4.w = 0u;
        *(uint4*)(hist + tid * 4) = z4;
    }
    if (tid < QB) { prefS[tid] = 0u; remS[tid] = NKEEP; }
    RBAR();   // barrier 1: hist/prefS initialized before any atomic

    // per-tile: unpack K frags, 3 chained MFMAs, quarter-wave extraction
#define MFMA_TILE(U0, U1, T) do {                                             \
        bf16x8 bh_, bl_;                                                      \
        UNPK(U0, U1, bh_, bl_);                                               \
        f32x4 acc_ = {0.f, 0.f, 0.f, 0.f};                                    \
        acc_ = __builtin_amdgcn_mfma_f32_16x16x32_bf16(al, bh_, acc_, 0, 0, 0); \
        acc_ = __builtin_amdgcn_mfma_f32_16x16x32_bf16(ah, bl_, acc_, 0, 0, 0); \
        acc_ = __builtin_amdgcn_mfma_f32_16x16x32_bf16(ah, bh_, acc_, 0, 0, 0); \
        if (l < 16) {                                                         \
            const int col_ = (w << 9) + ((T) << 4) + l;                       \
            sbuf[0 * SSTR + col_] = acc_[0];                                  \
            sbuf[1 * SSTR + col_] = acc_[1];                                  \
            sbuf[2 * SSTR + col_] = acc_[2];                                  \
            sbuf[3 * SSTR + col_] = acc_[3];                                  \
            atomicAdd(&hist[0 * 256 + (f2key(acc_[0]) >> 24)], 1u);           \
            atomicAdd(&hist[1 * 256 + (f2key(acc_[1]) >> 24)], 1u);           \
            atomicAdd(&hist[2 * 256 + (f2key(acc_[2]) >> 24)], 1u);           \
            atomicAdd(&hist[3 * 256 + (f2key(acc_[3]) >> 24)], 1u);           \
        }                                                                     \
    } while (0)

    // ---- Phase B: MFMA scores + top-byte histogram, 2-deep load pipeline ----
    uint4 kua0 = *(const uint4*)(KADDR(0)), kua1 = *(const uint4*)(KADDR(0) + 4);
    uint4 kub0 = *(const uint4*)(KADDR(1)), kub1 = *(const uint4*)(KADDR(1) + 4);
    #pragma unroll 1
    for (int t = 0; t < NT2; t += 2) {
        uint4 c0 = kua0, c1 = kua1;
        if (t + 2 < NT2) { kua0 = *(const uint4*)(KADDR(t + 2)); kua1 = *(const uint4*)(KADDR(t + 2) + 4); }
        MFMA_TILE(c0, c1, t);
        uint4 d0 = kub0, d1 = kub1;
        if (t + 3 < NT2) { kub0 = *(const uint4*)(KADDR(t + 3)); kub1 = *(const uint4*)(KADDR(t + 3) + 4); }
        MFMA_TILE(d0, d1, t + 1);
    }
    // preload V tiles 0..3 into registers; latency hides under radix/softmax
    float4 va0 = *(const float4*)(VADDR(0)), va1 = *(const float4*)(VADDR(0) + 16);
    float4 vb0 = *(const float4*)(VADDR(1)), vb1 = *(const float4*)(VADDR(1) + 16);
    float4 vc0 = *(const float4*)(VADDR(2)), vc1 = *(const float4*)(VADDR(2) + 16);
    float4 vd0 = *(const float4*)(VADDR(3)), vd1 = *(const float4*)(VADDR(3) + 16);
    RBAR();   // barrier 2: all scores + histogram atomics visible

    // ---- Phase C: exact 614th-largest per row. Wave w owns row w only. ----
    unsigned int* hrow = hist + w * 256;
    #pragma unroll 1
    for (int pass = 3; pass >= 0; --pass) {
        const int sh = pass * 8;
        const unsigned int pr = prefS[w];
        const int remv = remS[w];
        if (pass != 3) {
            const unsigned int hmsk = 0xFFFFFFFFu << (sh + 8);
            uint4 z4; z4.x = 0u; z4.y = 0u; z4.z = 0u; z4.w = 0u;
            *(uint4*)(hrow + l * 4) = z4;
            LGKM0();
            #pragma unroll 2
            for (int e = 0; e < 8; ++e) {
                float4 v = *(const float4*)&sbuf[w * SSTR + l * 4 + 256 * e];
                unsigned int k0 = f2key(v.x), k1 = f2key(v.y), k2 = f2key(v.z), k3 = f2key(v.w);
                if ((k0 & hmsk) == pr) atomicAdd(&hrow[(k0 >> sh) & 255u], 1u);
                if ((k1 & hmsk) == pr) atomicAdd(&hrow[(k1 >> sh) & 255u], 1u);
                if ((k2 & hmsk) == pr) atomicAdd(&hrow[(k2 >> sh) & 255u], 1u);
                if ((k3 & hmsk) == pr) atomicAdd(&hrow[(k3 >> sh) & 255u], 1u);
            }
            LGKM0();
        }
        uint4 c4 = *(const uint4*)(hrow + l * 4);
        unsigned int cnt[4] = { c4.x, c4.y, c4.z, c4.w };
        unsigned int part = cnt[0] + cnt[1] + cnt[2] + cnt[3];
        unsigned int suf = part;
        #pragma unroll
        for (int dlt = 1; dlt < 64; dlt <<= 1) {
            unsigned int v = __shfl_down(suf, dlt);
            if (l + dlt < 64) suf += v;
        }
        unsigned int run = suf - part;   // elems in bins owned by lanes > l
        #pragma unroll
        for (int i = 3; i >= 0; --i) {
            if ((int)run < remv && remv <= (int)(run + cnt[i])) {
                remS[w]  = remv - (int)run;
                prefS[w] = pr | ((unsigned int)(l * 4 + i) << sh);
            }
            run += cnt[i];
        }
        LGKM0();  // pref/rem visible wave-wide before next pass
    }

    // ---- Phase D: masked softmax on row w (float4, in LDS) ----
    {
        unsigned int key = prefS[w];
        unsigned int u = (key & 0x80000000u) ? (key & 0x7FFFFFFFu) : ~key;
        const float thr = __uint_as_float(u);
        float mx = 0.f;   // >=1434 masked zeros always present
        #pragma unroll 2
        for (int e = 0; e < 8; ++e) {
            float* sp = &sbuf[w * SSTR + l * 4 + 256 * e];
            float4 v = *(const float4*)sp;
            v.x = (v.x >= thr) ? v.x : 0.f;
            v.y = (v.y >= thr) ? v.y : 0.f;
            v.z = (v.z >= thr) ? v.z : 0.f;
            v.w = (v.w >= thr) ? v.w : 0.f;
            *(float4*)sp = v;
            mx = fmaxf(mx, fmaxf(fmaxf(v.x, v.y), fmaxf(v.z, v.w)));
        }
        #pragma unroll
        for (int d2 = 32; d2 >= 1; d2 >>= 1) mx = fmaxf(mx, __shfl_xor(mx, d2));
        float Z = 0.f;
        const float cm = __expf(0.f - mx);   // masked-entry value
        if (thr > 0.f) {
            // kept values >= thr > 0, masked == 0 exactly -> v>0 discriminates
            #pragma unroll 2
            for (int e = 0; e < 8; ++e) {
                float* sp = &sbuf[w * SSTR + l * 4 + 256 * e];
                float4 v = *(const float4*)sp;
                v.x = (v.x > 0.f) ? __expf(v.x - mx) : cm;
                v.y = (v.y > 0.f) ? __expf(v.y - mx) : cm;
                v.z = (v.z > 0.f) ? __expf(v.z - mx) : cm;
                v.w = (v.w > 0.f) ? __expf(v.w - mx) : cm;
                *(float4*)sp = v;
                Z += v.x + v.y + v.z + v.w;
            }
        } else {
            #pragma unroll 2
            for (int e = 0; e < 8; ++e) {
                float* sp = &sbuf[w * SSTR + l * 4 + 256 * e];
                float4 v = *(const float4*)sp;
                v.x = __expf(v.x - mx); v.y = __expf(v.y - mx);
                v.z = __expf(v.z - mx); v.w = __expf(v.w - mx);
                *(float4*)sp = v;
                Z += v.x + v.y + v.z + v.w;
            }
        }
        #pragma unroll
        for (int d2 = 32; d2 >= 1; d2 >>= 1) Z += __shfl_xor(Z, d2);
        if (l == 0) zS[w] = Z;
    }
    RBAR();   // barrier 3: all rows' p-values + zS visible

    // ---- Phase E: PV. 4-deep register pipeline over V, no barriers. ----
    float4 oa0, oa1, oa2, oa3, ob0, ob1, ob2, ob3;
    oa0.x=0;oa0.y=0;oa0.z=0;oa0.w=0; ob0=oa0; oa1=oa0; ob1=oa0;
    oa2=oa0; ob2=oa0; oa3=oa0; ob3=oa0;

#define PV_TILE(V0, V1, T) do {                                               \
        const int col = (w << 9) + ((T) << 4) + jg;                           \
        float p0 = sbuf[0 * SSTR + col];                                      \
        float p1 = sbuf[1 * SSTR + col];                                      \
        float p2 = sbuf[2 * SSTR + col];                                      \
        float p3 = sbuf[3 * SSTR + col];                                      \
        oa0.x=fmaf(p0,(V0).x,oa0.x); oa0.y=fmaf(p0,(V0).y,oa0.y); oa0.z=fmaf(p0,(V0).z,oa0.z); oa0.w=fmaf(p0,(V0).w,oa0.w); \
        ob0.x=fmaf(p0,(V1).x,ob0.x); ob0.y=fmaf(p0,(V1).y,ob0.y); ob0.z=fmaf(p0,(V1).z,ob0.z); ob0.w=fmaf(p0,(V1).w,ob0.w); \
        oa1.x=fmaf(p1,(V0).x,oa1.x); oa1.y=fmaf(p1,(V0).y,oa1.y); oa1.z=fmaf(p1,(V0).z,oa1.z); oa1.w=fmaf(p1,(V0).w,oa1.w); \
        ob1.x=fmaf(p1,(V1).x,ob1.x); ob1.y=fmaf(p1,(V1).y,ob1.y); ob1.z=fmaf(p1,(V1).z,ob1.z); ob1.w=fmaf(p1,(V1).w,ob1.w); \
        oa2.x=fmaf(p2,(V0).x,oa2.x); oa2.y=fmaf(p2,(V0).y,oa2.y); oa2.z=fmaf(p2,(V0).z,oa2.z); oa2.w=fmaf(p2,(V0).w,oa2.w); \
        ob2.x=fmaf(p2,(V1).x,ob2.x); ob2.y=fmaf(p2,(V1).y,ob2.y); ob2.z=fmaf(p2,(V1).z,ob2.z); ob2.w=fmaf(p2,(V1).w,ob2.w); \
        oa3.x=fmaf(p3,(V0).x,oa3.x); oa3.y=fmaf(p3,(V0).y,oa3.y); oa3.z=fmaf(p3,(V0).z,oa3.z); oa3.w=fmaf(p3,(V0).w,oa3.w); \
        ob3.x=fmaf(p3,(V1).x,ob3.x); ob3.y=fmaf(p3,(V1).y,ob3.y); ob3.z=fmaf(p3,(V1).z,ob3.z); ob3.w=fmaf(p3,(V1).w,ob3.w); \
    } while (0)

    #pragma unroll 1
    for (int t = 0; t < NT2; t += 4) {
        float4 c0, c1;
        c0 = va0; c1 = va1;
        if (t + 4 < NT2) { va0 = *(const float4*)(VADDR(t + 4)); va1 = *(const float4*)(VADDR(t + 4) + 16); }
        PV_TILE(c0, c1, t);
        c0 = vb0; c1 = vb1;
        if (t + 5 < NT2) { vb0 = *(const float4*)(VADDR(t + 5)); vb1 = *(const float4*)(VADDR(t + 5) + 16); }
        PV_TILE(c0, c1, t + 1);
        c0 = vc0; c1 = vc1;
        if (t + 6 < NT2) { vc0 = *(const float4*)(VADDR(t + 6)); vc1 = *(const float4*)(VADDR(t + 6) + 16); }
        PV_TILE(c0, c1, t + 2);
        c0 = vd0; c1 = vd1;
        if (t + 7 < NT2) { vd0 = *(const float4*)(VADDR(t + 7)); vd1 = *(const float4*)(VADDR(t + 7) + 16); }
        PV_TILE(c0, c1, t + 3);
    }
    RBAR();   // barrier 4: all p-value reads done; sbuf reusable as partials

    // reduce over the 16 column-groups (lanes differing in bits 2..5)
    #pragma unroll
    for (int d2 = 4; d2 <= 32; d2 <<= 1) {
        oa0.x+=__shfl_xor(oa0.x,d2); oa0.y+=__shfl_xor(oa0.y,d2); oa0.z+=__shfl_xor(oa0.z,d2); oa0.w+=__shfl_xor(oa0.w,d2);
        ob0.x+=__shfl_xor(ob0.x,d2); ob0.y+=__shfl_xor(ob0.y,d2); ob0.z+=__shfl_xor(ob0.z,d2); ob0.w+=__shfl_xor(ob0.w,d2);
        oa1.x+=__shfl_xor(oa1.x,d2); oa1.y+=__shfl_xor(oa1.y,d2); oa1.z+=__shfl_xor(oa1.z,d2); oa1.w+=__shfl_xor(oa1.w,d2);
        ob1.x+=__shfl_xor(ob1.x,d2); ob1.y+=__shfl_xor(ob1.y,d2); ob1.z+=__shfl_xor(ob1.z,d2); ob1.w+=__shfl_xor(ob1.w,d2);
        oa2.x+=__shfl_xor(oa2.x,d2); oa2.y+=__shfl_xor(oa2.y,d2); oa2.z+=__shfl_xor(oa2.z,d2); oa2.w+=__shfl_xor(oa2.w,d2);
        ob2.x+=__shfl_xor(ob2.x,d2); ob2.y+=__shfl_xor(ob2.y,d2); ob2.z+=__shfl_xor(ob2.z,d2); ob2.w+=__shfl_xor(ob2.w,d2);
        oa3.x+=__shfl_xor(oa3.x,d2); oa3.y+=__shfl_xor(oa3.y,d2); oa3.z+=__shfl_xor(oa3.z,d2); oa3.w+=__shfl_xor(oa3.w,d2);
        ob3.x+=__shfl_xor(ob3.x,d2); ob3.y+=__shfl_xor(ob3.y,d2); ob3.z+=__shfl_xor(ob3.z,d2); ob3.w+=__shfl_xor(ob3.w,d2);
    }
    // lanes 0..3 of each wave hold dims [4l,4l+4) (oa) and [16+4l,..) (ob)
    if (l < 4) {
        float* part = &sbuf[0];   // [4 waves][4 rows][32 dims]
        *(float4*)&part[(w * 4 + 0) * 32 + l * 4]      = oa0;
        *(float4*)&part[(w * 4 + 0) * 32 + 16 + l * 4] = ob0;
        *(float4*)&part[(w * 4 + 1) * 32 + l * 4]      = oa1;
        *(float4*)&part[(w * 4 + 1) * 32 + 16 + l * 4] = ob1;
        *(float4*)&part[(w * 4 + 2) * 32 + l * 4]      = oa2;
        *(float4*)&part[(w * 4 + 2) * 32 + 16 + l * 4] = ob2;
        *(float4*)&part[(w * 4 + 3) * 32 + l * 4]      = oa3;
        *(float4*)&part[(w * 4 + 3) * 32 + 16 + l * 4] = ob3;
    }
    RBAR();   // barrier 5
    if (tid < 128) {
        const int r = tid >> 5, d = tid & 31;
        const float* part = &sbuf[0];
        float o = part[(0 * 4 + r) * 32 + d] + part[(1 * 4 + r) * 32 + d]
                + part[(2 * 4 + r) * 32 + d] + part[(3 * 4 + r) * 32 + d];
        o /= zS[r];
        aout[((size_t)b * NSEQ + n0 + r) * CDIM + h * 32 + d] = o;
    }
}

// -------------------------------------------------------------------------
extern "C" void kernel_launch(void* const* d_in, const int* in_sizes, int n_in,
                              void* d_out, int out_size, void* d_ws, size_t ws_size,
                              hipStream_t stream) {
    (void)in_sizes; (void)n_in; (void)out_size; (void)ws_size;
    const float* x      = (const float*)d_in[0];
    const float* w_qkv  = (const float*)d_in[1];
    const float* b_qkv  = (const float*)d_in[2];
    const float* w_proj = (const float*)d_in[3];
    const float* b_proj = (const float*)d_in[4];
    float* out = (float*)d_out;

    const int M = BDIM * NSEQ;  // 8192
    float* qkv_ws  = (float*)d_ws;                       // 25.2 MB
    float* attn_ws = qkv_ws + (size_t)M * 768;           // 8.4 MB

    // 1) QKV GEMM -> [B][N][3][H][D]
    dim3 g1(M / 64, 768 / 64);
    gemm_nt_bias<<<g1, 256, 0, stream>>>(x, w_qkv, b_qkv, qkv_ws, M, 768, 256);

    // 1b) repack K section in place as (bf16_hi<<16)|bf16_lo
    pack_k<<<BDIM * NSEQ * 64 / 256, 256, 0, stream>>>(qkv_ws);

    // 2) fused sparse attention -> [B][N][C]
    sparse_attn<<<BDIM * NHEADS * (NSEQ / QB), 256, 0, stream>>>(qkv_ws, attn_ws);

    // 3) projection GEMM -> d_out
    dim3 g2(M / 64, 256 / 64);
    gemm_nt_bias<<<g2, 256, 0, stream>>>(attn_ws, w_proj, b_proj, out, M, 256, 256);
}